// Round 1
// 307.954 us; speedup vs baseline: 1.0218x; 1.0218x over previous
//
#include <hip/hip_runtime.h>

typedef float f32x4 __attribute__((ext_vector_type(4)));

// Problem constants (from reference setup_inputs)
constexpr int kB = 16, kQ = 900, kC = 91, kT = 4800;
constexpr int kBQ = kB * kQ;          // 14400
constexpr int kTI = 16;               // queries (i rows) per block
constexpr int kJT = 4;                // targets (j) per thread -> dwordx4 stores
constexpr int kBT = 256;              // threads per block
constexpr int kJB = kBT * kJT;        // 1024 j per block
constexpr int kCDS = 20;              // LDS cdT row stride (floats): 16 data + 4 pad
                                      // -> 80B stride: 16B-aligned for b128, banks
                                      //    spread over all 8 4-bank groups (20*tco mod 32)

// ---------------------------------------------------------------------------
// Kernel A: precompute weighted focal class-cost table cd[BQ, C]
//   cd = W_CLASS * (pos_cost - neg_cost)
// ---------------------------------------------------------------------------
__global__ __launch_bounds__(256)
void class_cost_kernel(const float* __restrict__ logits,
                       float* __restrict__ cd, int n) {
    int idx = blockIdx.x * 256 + threadIdx.x;
    if (idx >= n) return;
    float x = logits[idx];
    float p = 1.0f / (1.0f + expf(-x));          // sigmoid, fp32 like ref
    float omp = 1.0f - p;
    float pos = 0.25f * omp * omp * (-logf(p + 1e-8f));
    float neg = 0.75f * p * p * (-logf(omp + 1e-8f));
    cd[idx] = 2.0f * (pos - neg);                // W_CLASS folded in
}

// ---------------------------------------------------------------------------
// Kernel B: cost matrix out[BQ, T]
//   grid = (ceil(T/1024), BQ/16), block = 256
//   Thread owns 4 consecutive j, loops 16 i's (4 groups of 4).
//   cd tile staged TRANSPOSED in LDS ([c][i], stride 20): the 16 cd values a
//   thread needs per target are a column -> one ds_read_b128 per (target,
//   4-i-group) instead of a per-element ds_read_b32 gather.
// ---------------------------------------------------------------------------
__global__ __launch_bounds__(256)
void cost_kernel(const float* __restrict__ pred_boxes,   // [BQ,4] cxcywh
                 const int*   __restrict__ tgt_ids,      // [T] 1-based
                 const float* __restrict__ tgt_boxes,    // [T,4] cxcywh
                 const float* __restrict__ cd,           // [BQ,C] weighted
                 float*       __restrict__ out) {        // [BQ,T]
    __shared__ float  lds_cdT[kC * kCDS];  // 91 x 20 x 4B = 7280 B, [c][i]
    __shared__ float4 lds_pb[kTI];         // 16 pred boxes (raw cxcywh)

    const int tid = threadIdx.x;
    const int i0  = blockIdx.y * kTI;
    const int j0  = blockIdx.x * kJB + tid * kJT;

    // Stage cd rows i0..i0+15 transposed: global read coalesced (row-major),
    // LDS write scattered (6 iterations total -> negligible).
    for (int k = tid; k < kTI * kC; k += kBT) {
        int i = k / kC, c = k - i * kC;
        lds_cdT[c * kCDS + i] = cd[(i0 + i) * kC + c];
    }
    if (tid < kTI)
        lds_pb[tid] = reinterpret_cast<const float4*>(pred_boxes)[i0 + tid];
    __syncthreads();

    // T%4==0 -> all-or-nothing per thread. Single barrier above, so a
    // divergent whole-thread exit here is safe; wave 3 of the tail block
    // retires entirely.
    if (j0 + kJT > kT) return;

    // Per-thread target data: load + convert ONCE (reused across 16 i's)
    int4 ids = *reinterpret_cast<const int4*>(&tgt_ids[j0]);
    int tco[kJT] = {ids.x - 1, ids.y - 1, ids.z - 1, ids.w - 1};
    float tcx[kJT], tcy[kJT], tw[kJT], th[kJT];
    float tx0[kJT], ty0[kJT], tx1[kJT], ty1[kJT], ta[kJT];
    #pragma unroll
    for (int q = 0; q < kJT; ++q) {
        float4 tb = reinterpret_cast<const float4*>(tgt_boxes)[j0 + q];
        tcx[q] = tb.x; tcy[q] = tb.y; tw[q] = tb.z; th[q] = tb.w;
        tx0[q] = tb.x - 0.5f * tb.z;  ty0[q] = tb.y - 0.5f * tb.w;
        tx1[q] = tb.x + 0.5f * tb.z;  ty1[q] = tb.y + 0.5f * tb.w;
        ta[q]  = tb.z * tb.w;
    }

    const size_t row0 = (size_t)i0 * kT + j0;

    #pragma unroll 1   // keep cdv working set at 16 VGPRs (don't batch all 64)
    for (int ig = 0; ig < kTI / 4; ++ig) {
        // One b128 per target: cd[i0+ig*4 .. i0+ig*4+3][tco[q]]
        f32x4 cdv[kJT];
        #pragma unroll
        for (int q = 0; q < kJT; ++q)
            cdv[q] = *reinterpret_cast<const f32x4*>(
                         &lds_cdT[tco[q] * kCDS + ig * 4]);

        #pragma unroll
        for (int i2 = 0; i2 < 4; ++i2) {
            const int ii = ig * 4 + i2;
            const float4 pb = lds_pb[ii];       // broadcast ds_read_b128
            const float pcx = pb.x, pcy = pb.y, pw = pb.z, ph = pb.w;
            const float px0 = pcx - 0.5f * pw, py0 = pcy - 0.5f * ph;
            const float px1 = pcx + 0.5f * pw, py1 = pcy + 0.5f * ph;
            const float pa  = pw * ph;

            f32x4 res;
            #pragma unroll
            for (int q = 0; q < kJT; ++q) {
                const float cdvq = cdv[q][i2];  // static index -> register

                float dx = pcx - tcx[q], dy = pcy - tcy[q];
                float dw = pw  - tw[q],  dh = ph  - th[q];
                float l1 = (fabsf(dx) + fabsf(dy)) + (fabsf(dw) + fabsf(dh));

                float lx = fmaxf(px0, tx0[q]), ly = fmaxf(py0, ty0[q]);
                float rx = fminf(px1, tx1[q]), ry = fminf(py1, ty1[q]);
                float iwr = rx - lx, ihr = ry - ly;
                float inter = fmaxf(iwr, 0.f) * fmaxf(ihr, 0.f);

                // max(a,b) = a+b-min(a,b): enclosing box w/o extra min/max.
                // ew = pw+tw-iwr >= max(pw,tw) >= 0 exactly -> no clamp.
                float ew  = (pw + tw[q]) - iwr;
                float eh  = (ph + th[q]) - ihr;
                float enc = ew * eh;
                float uni = (pa + ta[q]) - inter;

                float rcpu = __builtin_amdgcn_rcpf(fmaxf(uni, 1e-6f));
                float rcpe = __builtin_amdgcn_rcpf(fmaxf(enc, 1e-6f));

                // c = cd + 5*l1 - 2*iou + 2*(enc-uni)/enc   (exact ref form)
                float c = fmaf(5.0f, l1, cdvq);
                c = fmaf(-2.0f, inter * rcpu, c);
                c = fmaf( 2.0f, (enc - uni) * rcpe, c);
                res[q] = c;
            }

            // Streaming output, zero reuse -> keep it out of L2.
            __builtin_nontemporal_store(res,
                reinterpret_cast<f32x4*>(&out[row0 + (size_t)ii * kT]));
        }
    }
}

extern "C" void kernel_launch(void* const* d_in, const int* in_sizes, int n_in,
                              void* d_out, int out_size, void* d_ws, size_t ws_size,
                              hipStream_t stream) {
    const float* logits  = (const float*)d_in[0];   // [16,900,91]
    const float* pboxes  = (const float*)d_in[1];   // [16,900,4]
    const int*   tids    = (const int*)d_in[2];     // [4800]
    const float* tboxes  = (const float*)d_in[3];   // [4800,4]
    float* out = (float*)d_out;                     // [16,900,4800]
    float* cd  = (float*)d_ws;                      // [14400,91] = 5.24 MB

    const int n_cd = kBQ * kC;
    class_cost_kernel<<<(n_cd + 255) / 256, 256, 0, stream>>>(logits, cd, n_cd);

    dim3 grid((kT + kJB - 1) / kJB, kBQ / kTI);     // (5, 900)
    cost_kernel<<<grid, 256, 0, stream>>>(pboxes, tids, tboxes, cd, out);
}